// Round 1
// baseline (76.651 us; speedup 1.0000x reference)
//
#include <hip/hip_runtime.h>

#define GRID   64
#define BATCH  4
#define NV     512
#define NP     8192
#define NNET   2000
#define MAXPIN 8
#define NB     32          // nets per block
#define NCHUNK 63          // ceil(2000/32)

__device__ __forceinline__ float sigmoidf_fast(float z) {
    return 1.0f / (1.0f + __expf(-z));
}

__global__ __launch_bounds__(256)
void rudy_accum_kernel(const float* __restrict__ positions,
                       const float* __restrict__ pin_offsets,
                       const int*   __restrict__ net_to_pin,
                       const int*   __restrict__ pin_to_macro,
                       float* __restrict__ rudy) {
    const int chunk = blockIdx.x;
    const int b     = blockIdx.y;
    const int t     = threadIdx.x;

    __shared__ float s_inx[NB][GRID];
    __shared__ float s_iny[NB][GRID];
    __shared__ float s_xmin[NB], s_xmax[NB], s_ymin[NB], s_ymax[NB], s_inv[NB];

    // ---- Phase A1: bbox per net, 8 lanes cooperate per net (shuffle reduce) ----
    {
        const int nl = t >> 3;      // local net 0..31
        const int j  = t & 7;       // pin slot
        const int n  = chunk * NB + nl;
        int pi = (n < NNET) ? net_to_pin[n * MAXPIN + j] : -1;
        int sp = pi > 0 ? pi : 0;
        int v  = pin_to_macro[sp];
        float px = positions[(b * NV + v) * 2 + 0] + pin_offsets[sp * 2 + 0];
        float py = positions[(b * NV + v) * 2 + 1] + pin_offsets[sp * 2 + 1];
        bool valid = pi >= 0;
        float xmx = valid ? px : -1e9f;
        float xmn = valid ? px :  1e9f;
        float ymx = valid ? py : -1e9f;
        float ymn = valid ? py :  1e9f;
        #pragma unroll
        for (int off = 1; off < 8; off <<= 1) {
            xmx = fmaxf(xmx, __shfl_xor(xmx, off, 64));
            xmn = fminf(xmn, __shfl_xor(xmn, off, 64));
            ymx = fmaxf(ymx, __shfl_xor(ymx, off, 64));
            ymn = fminf(ymn, __shfl_xor(ymn, off, 64));
        }
        if (j == 0) {
            float xming = (xmn + 1.0f) * 31.5f;   // (v+1)*0.5*(M-1)
            float xmaxg = (xmx + 1.0f) * 31.5f;
            float yming = (ymn + 1.0f) * 31.5f;
            float ymaxg = (ymx + 1.0f) * 31.5f;
            float size = fmaxf((xmaxg - xming + 1.0f) * (ymaxg - yming + 1.0f), 1.0f);
            s_xmin[nl] = xming; s_xmax[nl] = xmaxg;
            s_ymin[nl] = yming; s_ymax[nl] = ymaxg;
            s_inv[nl]  = 1.0f / size;
        }
    }
    __syncthreads();

    // ---- Phase A2: fill in_x / in_y (NB*128 = 4096 values, 16 per thread) ----
    #pragma unroll
    for (int i = 0; i < 16; ++i) {
        int v     = i * 256 + t;
        int n     = v >> 7;          // net
        int rem   = v & 127;
        int which = rem >> 6;        // 0 = x, 1 = y
        int coord = rem & 63;
        float c  = (float)coord;
        float lo = which ? s_ymin[n] : s_xmin[n];
        float hi = which ? s_ymax[n] : s_xmax[n];
        float val = sigmoidf_fast(2.0f * (c - lo + 0.5f)) *
                    sigmoidf_fast(2.0f * (hi - c + 0.5f));
        if (which) s_iny[n][coord] = val; else s_inx[n][coord] = val;
    }
    __syncthreads();

    // ---- Phase C: register-accumulate 16 cells/thread over all NB nets ----
    const int lane = t & 63;        // = x coordinate (conflict-free LDS reads)
    const int w    = t >> 6;        // wave id: owns rows y = w*16 .. w*16+15
    float acc[16];
    #pragma unroll
    for (int k = 0; k < 16; ++k) acc[k] = 0.0f;

    for (int n = 0; n < NB; ++n) {
        float xv = s_inx[n][lane] * s_inv[n];
        const float4* iny4 = (const float4*)&s_iny[n][w * 16];  // 64B-aligned, wave-uniform
        #pragma unroll
        for (int k4 = 0; k4 < 4; ++k4) {
            float4 yv = iny4[k4];
            acc[k4 * 4 + 0] += yv.x * xv;
            acc[k4 * 4 + 1] += yv.y * xv;
            acc[k4 * 4 + 2] += yv.z * xv;
            acc[k4 * 4 + 3] += yv.w * xv;
        }
    }

    float* dst = rudy + b * (GRID * GRID);
    #pragma unroll
    for (int k = 0; k < 16; ++k) {
        int cell = (w * 16 + k) * GRID + lane;
        atomicAdd(&dst[cell], acc[k]);
    }
}

__global__ __launch_bounds__(256)
void smooth_penalty_kernel(const float* __restrict__ rudy,
                           float* __restrict__ out_penalty,
                           float* __restrict__ out_smooth) {
    const int b = blockIdx.x;
    const int t = threadIdx.x;

    __shared__ float tile[GRID * GRID];
    __shared__ float tmp [GRID * GRID];
    __shared__ float red[4];

    // 1D gaussian, sigma=1.5, ksize=7, normalized (separable == normalized 2D)
    float g[7];
    {
        float s = 0.0f;
        #pragma unroll
        for (int i = 0; i < 7; ++i) {
            float d = (float)(i - 3);
            g[i] = expf(-d * d / 4.5f);
            s += g[i];
        }
        float inv = 1.0f / s;
        #pragma unroll
        for (int i = 0; i < 7; ++i) g[i] *= inv;
    }

    const float* src = rudy + b * GRID * GRID;
    #pragma unroll
    for (int k = 0; k < 16; ++k) tile[k * 256 + t] = src[k * 256 + t];
    __syncthreads();

    // horizontal pass (zero padding)
    #pragma unroll
    for (int k = 0; k < 16; ++k) {
        int c = k * 256 + t;
        int y = c >> 6, x = c & 63;
        float s = 0.0f;
        #pragma unroll
        for (int d = -3; d <= 3; ++d) {
            int xx = x + d;
            if (xx >= 0 && xx < GRID) s += g[d + 3] * tile[y * GRID + xx];
        }
        tmp[c] = s;
    }
    __syncthreads();

    // vertical pass + outputs + penalty
    float local = 0.0f;
    #pragma unroll
    for (int k = 0; k < 16; ++k) {
        int c = k * 256 + t;
        int y = c >> 6, x = c & 63;
        float s = 0.0f;
        #pragma unroll
        for (int d = -3; d <= 3; ++d) {
            int yy = y + d;
            if (yy >= 0 && yy < GRID) s += g[d + 3] * tmp[yy * GRID + x];
        }
        out_smooth[b * GRID * GRID + c] = s;
        float ov = s - 1.0f;
        ov = ov > 0.0f ? ov : 0.0f;
        local += ov * ov;
    }

    // block reduce
    #pragma unroll
    for (int off = 32; off > 0; off >>= 1) local += __shfl_down(local, off, 64);
    if ((t & 63) == 0) red[t >> 6] = local;
    __syncthreads();
    if (t == 0) out_penalty[b] = red[0] + red[1] + red[2] + red[3];
}

extern "C" void kernel_launch(void* const* d_in, const int* in_sizes, int n_in,
                              void* d_out, int out_size, void* d_ws, size_t ws_size,
                              hipStream_t stream) {
    const float* positions    = (const float*)d_in[0];
    const float* pin_offsets  = (const float*)d_in[1];
    const int*   net_to_pin   = (const int*)d_in[2];
    const int*   pin_to_macro = (const int*)d_in[3];
    float* out  = (float*)d_out;                 // [0..3] penalty, [4..] rudy_smooth
    float* rudy = (float*)d_ws;                  // B*64*64 f32 accumulator

    hipMemsetAsync(d_ws, 0, BATCH * GRID * GRID * sizeof(float), stream);
    rudy_accum_kernel<<<dim3(NCHUNK, BATCH), 256, 0, stream>>>(
        positions, pin_offsets, net_to_pin, pin_to_macro, rudy);
    smooth_penalty_kernel<<<BATCH, 256, 0, stream>>>(rudy, out, out + BATCH);
}